// Round 3
// baseline (1265.503 us; speedup 1.0000x reference)
//
#include <hip/hip_runtime.h>

// XOR chain = inclusive prefix-XOR along axis 0 of [S=4096, B=8192] int32.
// Round 3: single-pass chained scan (decoupled lookback, aggregate-only).
// Each block: ticket -> load 32 rows into regs -> local inclusive XOR ->
// publish aggregate (release flag) -> XOR all predecessor aggregates
// (batched flag polls, L2-resident 4 MiB table) -> write output once.
// HBM floor: 128 MiB read + 128 MiB write = 256 MiB ~= 40 us @ 6.3 TB/s.

#define S 4096
#define B4 2048            // uint4 column-groups per row
#define R 32               // rows per chunk
#define NCHUNK (S / R)     // 128
#define TPB 256
#define NCT (B4 / TPB)     // 8 column tiles
#define NBLK (NCHUNK * NCT)

typedef unsigned int v4u __attribute__((ext_vector_type(4)));

// ws layout: w[0] = ticket counter, w[4 .. 4+NBLK) = flags (0=not ready,
// 1=aggregate published). agg table at byte offset 16384: NBLK slots of
// TPB v4u (4 MiB).
__global__ __launch_bounds__(256) void ws_init(unsigned int* __restrict__ w) {
    int i = blockIdx.x * 256 + threadIdx.x;
    if (i < NBLK + 4) w[i] = 0u;
}

__global__ __launch_bounds__(TPB) void xor_scan_onepass(
        const v4u* __restrict__ in, v4u* __restrict__ out,
        unsigned int* __restrict__ wctl, v4u* __restrict__ agg) {
    __shared__ unsigned int sh_ticket;
    const int tid = threadIdx.x;
    if (tid == 0) sh_ticket = atomicAdd(&wctl[0], 1u);
    __syncthreads();
    const unsigned int t = sh_ticket;
    const int ct    = (int)(t & (NCT - 1));   // chain id (column tile)
    const int chunk = (int)(t >> 3);          // link id — ticket order
                                              // guarantees predecessors started
    const int colg  = ct * TPB + tid;
    unsigned int* flags = wctl + 4;

    // Load this chunk's 32 rows for my column-group; all 32 loads in flight.
    const v4u* p = in + (size_t)chunk * R * B4 + colg;
    v4u val[R];
#pragma unroll
    for (int r = 0; r < R; ++r) val[r] = p[(size_t)r * B4];
    // Local inclusive prefix in registers.
#pragma unroll
    for (int r = 1; r < R; ++r) val[r] ^= val[r - 1];

    // Publish aggregate for this (chunk, coltile).
    const int slot = chunk * NCT + ct;
    agg[(size_t)slot * TPB + tid] = val[R - 1];
    __syncthreads();
    if (tid == 0)
        __hip_atomic_store(&flags[slot], 1u, __ATOMIC_RELEASE,
                           __HIP_MEMORY_SCOPE_AGENT);

    // Exclusive prefix = XOR of all predecessor chunk aggregates in my chain.
    // Consume in batches of 8: poll 8 flags, then 8 independent 16 B loads.
    v4u excl = (v4u){0u, 0u, 0u, 0u};
    int done = 0;
    while (done < chunk) {
        int batch = chunk - done;
        if (batch > 8) batch = 8;
        if (tid == 0) {
            for (;;) {
                unsigned int ok = 1u;
                for (int j = 0; j < batch; ++j)
                    ok &= __hip_atomic_load(&flags[(done + j) * NCT + ct],
                                            __ATOMIC_RELAXED,
                                            __HIP_MEMORY_SCOPE_AGENT);
                if (ok) break;
                __builtin_amdgcn_s_sleep(8);
            }
        }
        __syncthreads();
        __threadfence();   // acquire: make predecessors' agg stores visible
        for (int j = 0; j < batch; ++j)
            excl ^= agg[(size_t)((done + j) * NCT + ct) * TPB + tid];
        done += batch;
    }

    // Write output: seed ^ local inclusive values. Nontemporal (no reuse).
    v4u* q = out + (size_t)chunk * R * B4 + colg;
#pragma unroll
    for (int r = 0; r < R; ++r)
        __builtin_nontemporal_store(excl ^ val[r], &q[(size_t)r * B4]);
}

extern "C" void kernel_launch(void* const* d_in, const int* in_sizes, int n_in,
                              void* d_out, int out_size, void* d_ws, size_t ws_size,
                              hipStream_t stream) {
    const v4u* in = (const v4u*)d_in[0];
    v4u* out = (v4u*)d_out;
    unsigned int* wctl = (unsigned int*)d_ws;
    v4u* agg = (v4u*)((char*)d_ws + 16384);   // 4 MiB aggregate table

    ws_init<<<(NBLK + 4 + 255) / 256, 256, 0, stream>>>(wctl);
    xor_scan_onepass<<<NBLK, TPB, 0, stream>>>(in, out, wctl, agg);
}

// Round 4
// 247.271 us; speedup vs baseline: 5.1179x; 5.1179x over previous
//
#include <hip/hip_runtime.h>

// XOR chain = inclusive prefix-XOR along axis 0 of [S=4096, B=8192] int32.
// Round 4: two bulk-synchronous kernels, no atomics/fences.
//   K1: per-chunk XOR totals -> ws (4 MiB, stays L2/LLC resident).
//   K3: each block redundantly XOR-reduces its chunk's exclusive prefix from
//       ws (L2 reads, ~8 us aggregate), then scans its 32 rows: cached input
//       loads (LLC-warm from K1), nontemporal output stores (pure stream,
//       don't evict the input from LLC).
// HBM floor: 128 MiB read + 128 MiB write (+ LLC-absorbed re-read) ~= 45 us.

#define S 4096
#define B4 2048            // uint4 column-groups per row
#define CHUNK 32           // rows per chunk
#define NCHUNK (S / CHUNK) // 128
#define TPB 256
#define NCT (B4 / TPB)     // 8 column tiles

typedef unsigned int v4u __attribute__((ext_vector_type(4)));

// K1: ws[chunk][colg] = XOR of the chunk's 32 rows, per uint4 column-group.
__global__ __launch_bounds__(TPB) void xor_chunk_total(
        const v4u* __restrict__ in, v4u* __restrict__ ws) {
    const int colg  = blockIdx.x * TPB + threadIdx.x;   // 0..B4-1
    const int chunk = blockIdx.y;
    const v4u* p = in + (size_t)chunk * CHUNK * B4 + colg;
    v4u acc = (v4u){0u, 0u, 0u, 0u};
#pragma unroll 16
    for (int r = 0; r < CHUNK; ++r) {
        acc ^= p[(size_t)r * B4];
    }
    ws[(size_t)chunk * B4 + colg] = acc;
}

// K3: redundant per-block exclusive-prefix reduce over chunk totals, then
// local inclusive scan + output write.
__global__ __launch_bounds__(TPB) void xor_scan_out(
        const v4u* __restrict__ in, const v4u* __restrict__ ws,
        v4u* __restrict__ out) {
    const int colg  = blockIdx.x * TPB + threadIdx.x;
    const int chunk = (NCHUNK - 1) - blockIdx.y;  // heavy blocks launch first

    // Exclusive prefix: XOR of ws[0..chunk) for my column-group.
    // All loads independent; ws is L2/LLC-resident (4 MiB).
    v4u excl = (v4u){0u, 0u, 0u, 0u};
#pragma unroll 8
    for (int c = 0; c < chunk; ++c) {
        excl ^= ws[(size_t)c * B4 + colg];
    }

    const v4u* p = in  + (size_t)chunk * CHUNK * B4 + colg;
    v4u*       q = out + (size_t)chunk * CHUNK * B4 + colg;
    v4u acc = excl;
#pragma unroll 8
    for (int r = 0; r < CHUNK; ++r) {
        acc ^= p[(size_t)r * B4];                          // cached: LLC-warm
        __builtin_nontemporal_store(acc, &q[(size_t)r * B4]);  // pure stream
    }
}

extern "C" void kernel_launch(void* const* d_in, const int* in_sizes, int n_in,
                              void* d_out, int out_size, void* d_ws, size_t ws_size,
                              hipStream_t stream) {
    const v4u* in = (const v4u*)d_in[0];
    v4u* out = (v4u*)d_out;
    v4u* ws  = (v4u*)d_ws;   // needs NCHUNK * B4 * 16 = 4 MiB

    dim3 grid(NCT, NCHUNK);  // 8 x 128 = 1024 blocks
    xor_chunk_total<<<grid, TPB, 0, stream>>>(in, ws);
    xor_scan_out<<<grid, TPB, 0, stream>>>(in, ws, out);
}